// Round 1
// baseline (297.701 us; speedup 1.0000x reference)
//
#include <hip/hip_runtime.h>
#include <hip/hip_bf16.h>

typedef __bf16 bf16x8 __attribute__((ext_vector_type(8)));
typedef float  f32x4  __attribute__((ext_vector_type(4)));

#define N_NODES 10000
#define N_EDGES 320000

// workspace byte offsets (all 16B aligned)
#define WS_TEMB   0u         // 128*256*4   = 131072
#define WS_H      131072u    // 10000*256*2 = 5120000  (h in bf16)
#define WS_W1AT   5251072u   // 256*256*2   = 131072   (atom W1^T [n][k])
#define WS_W2AT   5382144u   // 112*256*2   = 57344    (atom W2^T padded [112][256])
#define WS_W1BT   5439488u   // 256*512*2   = 262144   (bond W1^T [n][k=512])
#define WS_W2BT   5701632u   // 16*256*2    = 8192     (bond W2^T padded [16][256])

// ---------------- prep kernels ----------------

// dst[n][k] = (n < Ns) ? src[k][n] : 0   (dst is [Nd][K] bf16)
__global__ void tcast_kernel(const float* __restrict__ src, __hip_bfloat16* __restrict__ dst,
                             int K, int Ns, int Nd)
{
    int i = blockIdx.x * 256 + threadIdx.x;
    if (i >= Nd * K) return;
    int n = i / K, k = i - n * K;
    float v = (n < Ns) ? src[k * Ns + n] : 0.0f;
    dst[i] = __float2bfloat16(v);
}

// temb[b][0:128] = sin(t[b]*freq), temb[b][128:256] = cos(t[b]*freq)
__global__ void temb_kernel(const float* __restrict__ t, float* __restrict__ temb)
{
    int b = blockIdx.x;
    int i = threadIdx.x;   // 0..127
    float freq = expf((float)i * (-9.210340371976184f / 127.0f));
    float ang  = t[b] * freq;
    temb[b * 256 + i]       = sinf(ang);
    temb[b * 256 + 128 + i] = cosf(ang);
}

// h_bf16[n][c] = bf16(nf[n][c] + temb[batch[n]][c]); also copy nf -> out_nf
__global__ void h_kernel(const float* __restrict__ nf, const int* __restrict__ batch,
                         const float* __restrict__ temb, __hip_bfloat16* __restrict__ hb,
                         float* __restrict__ out_nf)
{
    int i = blockIdx.x * 256 + threadIdx.x;     // one thread per 8 elems
    if (i >= N_NODES * 32) return;
    int n = i >> 5;
    int c = (i & 31) << 3;
    const float4* p = (const float4*)(nf + (size_t)n * 256 + c);
    float4 v0 = p[0], v1 = p[1];
    int b = batch[n];
    const float4* q = (const float4*)(temb + (size_t)b * 256 + c);
    float4 t0 = q[0], t1 = q[1];
    union { int4 i4; __hip_bfloat16 h[8]; } u;
    u.h[0] = __float2bfloat16(v0.x + t0.x);
    u.h[1] = __float2bfloat16(v0.y + t0.y);
    u.h[2] = __float2bfloat16(v0.z + t0.z);
    u.h[3] = __float2bfloat16(v0.w + t0.w);
    u.h[4] = __float2bfloat16(v1.x + t1.x);
    u.h[5] = __float2bfloat16(v1.y + t1.y);
    u.h[6] = __float2bfloat16(v1.z + t1.z);
    u.h[7] = __float2bfloat16(v1.w + t1.w);
    *(int4*)((char*)hb + (size_t)n * 512 + (size_t)c * 2) = u.i4;
    float4* o = (float4*)(out_nf + (size_t)n * 256 + c);
    o[0] = v0; o[1] = v1;
}

__global__ void pos_copy_kernel(const float4* __restrict__ src, float4* __restrict__ dst)
{
    int i = blockIdx.x * 256 + threadIdx.x;
    if (i < 7500) dst[i] = src[i];   // 30000 floats
}

// ---------------- fused 2-layer MLP (MFMA) ----------------
//
// Layer 1: D1[64 x 256] = A[64 x K] @ W1[K x 256], K = KSTEPS*32
//   A rows: GATHER ? (k<K/2 ? h[row[e]] : h[col[e]]) : h[m]
//   4 waves, wave w owns n-slice [w*64, w*64+64): 4x4 frags of 16x16.
// Hidden: relu(D1 + b1) -> bf16 in LDS [64][264].
// Layer 2: out[64 x N2REAL] = Hid[64 x 256] @ W2[256 x N2F*16] (+b2), wave w owns rows [w*16,+16).
//
// LDS strides chosen so frag ds_reads are 16B-aligned and only 2-way bank-aliased:
//   stage rows 56 elems (112B), hidden rows 264 elems (528B).
template<int KSTEPS, bool GATHER, int N2F, int N2REAL>
__global__ __launch_bounds__(256) void mlp_kernel(
    const __hip_bfloat16* __restrict__ hb,    // [N_NODES][256] bf16
    const __hip_bfloat16* __restrict__ w1t,   // [256][KSTEPS*32] bf16 (n-major)
    const __hip_bfloat16* __restrict__ w2t,   // [N2F*16][256] bf16 (n-major)
    const float* __restrict__ b1,             // [256]
    const float* __restrict__ b2,             // [N2REAL]
    const int*  __restrict__ eidx,            // GATHER: [2][N_EDGES]
    int M,
    float* __restrict__ out)                  // [M][N2REAL]
{
    __shared__ int4 lds_raw[35840 / 16];
    char* lds = (char*)lds_raw;
    // region 0: A stage [64][56] bf16 (7168 B)
    // region 1: B stage [256][56] bf16 at +7168 (28672 B)
    // after layer 1 (aliased): hidden [64][264] bf16 (33792 B)
    __hip_bfloat16* Hid = (__hip_bfloat16*)lds;

    const int t  = threadIdx.x;
    const int w  = t >> 6;      // wave 0..3
    const int l  = t & 63;
    const int m0 = blockIdx.x * 64;

    // staging coords: A chunk per thread (row am, 16B chunk akc)
    const int am = t >> 2, akc = t & 3;
    long srcA0, srcA1 = 0;
    if (GATHER) {
        int ri = eidx[m0 + am];
        int ci = eidx[N_EDGES + m0 + am];
        srcA0 = (long)ri * 512 + akc * 16;
        srcA1 = (long)ci * 512 + akc * 16;
    } else {
        int r = m0 + am; if (r > M - 1) r = M - 1;
        srcA0 = (long)r * 512 + akc * 16;
    }
    const char* hbase  = (const char*)hb;
    const char* w1base = (const char*)w1t;

    f32x4 acc[4][4];
    const f32x4 zero4 = {0.f, 0.f, 0.f, 0.f};
    #pragma unroll
    for (int i = 0; i < 4; ++i)
        #pragma unroll
        for (int j = 0; j < 4; ++j) acc[i][j] = zero4;

    for (int ks = 0; ks < KSTEPS; ++ks) {
        __syncthreads();                     // previous step's frag reads done
        // stage A (64 rows x 32 k): 1 chunk/thread
        long aoff;
        if (GATHER) aoff = ((ks < KSTEPS / 2) ? srcA0 : srcA1) + (long)(ks & (KSTEPS / 2 - 1)) * 64;
        else        aoff = srcA0 + (long)ks * 64;
        int4 av = *(const int4*)(hbase + aoff);
        *(int4*)(lds + am * 112 + akc * 16) = av;
        // stage B (256 n x 32 k): 4 chunks/thread
        #pragma unroll
        for (int i = 0; i < 4; ++i) {
            int cchunk = t + i * 256;
            int n = cchunk >> 2, kc = cchunk & 3;
            int4 bv = *(const int4*)(w1base + (long)n * (KSTEPS * 64) + ks * 64 + kc * 16);
            *(int4*)(lds + 7168 + n * 112 + kc * 16) = bv;
        }
        __syncthreads();
        // fragments + MFMA
        bf16x8 af[4];
        #pragma unroll
        for (int mi = 0; mi < 4; ++mi)
            af[mi] = *(const bf16x8*)(lds + (mi * 16 + (l & 15)) * 112 + (l >> 4) * 16);
        #pragma unroll
        for (int ni = 0; ni < 4; ++ni) {
            bf16x8 bfr = *(const bf16x8*)(lds + 7168 + (w * 64 + ni * 16 + (l & 15)) * 112 + (l >> 4) * 16);
            #pragma unroll
            for (int mi = 0; mi < 4; ++mi)
                acc[mi][ni] = __builtin_amdgcn_mfma_f32_16x16x32_bf16(af[mi], bfr, acc[mi][ni], 0, 0, 0);
        }
    }

    // epilogue 1: hidden = relu(acc + b1) -> LDS bf16 (aliases stage; barrier first)
    __syncthreads();
    {
        float b1v[4];
        #pragma unroll
        for (int ni = 0; ni < 4; ++ni) b1v[ni] = b1[w * 64 + ni * 16 + (l & 15)];
        #pragma unroll
        for (int mi = 0; mi < 4; ++mi)
            #pragma unroll
            for (int ni = 0; ni < 4; ++ni)
                #pragma unroll
                for (int r = 0; r < 4; ++r) {
                    int m = mi * 16 + (l >> 4) * 4 + r;        // D row (m89-verified layout)
                    int n = w * 64 + ni * 16 + (l & 15);       // D col
                    float v = acc[mi][ni][r] + b1v[ni];
                    v = fmaxf(v, 0.0f);
                    Hid[m * 264 + n] = __float2bfloat16(v);
                }
    }
    __syncthreads();

    // layer 2: wave w owns rows [w*16, w*16+16); K=256 (8 steps); W2^T frags direct from global
    f32x4 acc2[N2F];
    #pragma unroll
    for (int i = 0; i < N2F; ++i) acc2[i] = zero4;
    const char* w2base = (const char*)w2t;
    #pragma unroll
    for (int ks = 0; ks < 8; ++ks) {
        bf16x8 a2 = *(const bf16x8*)(lds + (w * 16 + (l & 15)) * 528 + ks * 64 + (l >> 4) * 16);
        #pragma unroll
        for (int nf2 = 0; nf2 < N2F; ++nf2) {
            bf16x8 b2f = *(const bf16x8*)(w2base + (nf2 * 16 + (l & 15)) * 512 + ks * 64 + (l >> 4) * 16);
            acc2[nf2] = __builtin_amdgcn_mfma_f32_16x16x32_bf16(a2, b2f, acc2[nf2], 0, 0, 0);
        }
    }
    // epilogue 2: store out[m][n] for n < N2REAL
    #pragma unroll
    for (int nf2 = 0; nf2 < N2F; ++nf2) {
        int n = nf2 * 16 + (l & 15);
        if (n < N2REAL) {
            float b2v = b2[n];
            #pragma unroll
            for (int r = 0; r < 4; ++r) {
                int m  = w * 16 + (l >> 4) * 4 + r;
                int gm = m0 + m;
                if (gm < M)
                    out[(long)gm * N2REAL + n] = acc2[nf2][r] + b2v;
            }
        }
    }
}

// ---------------- launch ----------------

extern "C" void kernel_launch(void* const* d_in, const int* in_sizes, int n_in,
                              void* d_out, int out_size, void* d_ws, size_t ws_size,
                              hipStream_t stream)
{
    const float* node_features = (const float*)d_in[0];
    const float* pos_pred      = (const float*)d_in[1];
    const int*   edge_index    = (const int*)d_in[2];
    const int*   batch         = (const int*)d_in[3];
    const float* t_disc        = (const float*)d_in[4];
    const float* atom_w1       = (const float*)d_in[5];
    const float* atom_b1       = (const float*)d_in[6];
    const float* atom_w2       = (const float*)d_in[7];
    const float* atom_b2       = (const float*)d_in[8];
    const float* bond_w1       = (const float*)d_in[9];
    const float* bond_b1       = (const float*)d_in[10];
    const float* bond_w2       = (const float*)d_in[11];
    const float* bond_b2       = (const float*)d_in[12];

    char* ws = (char*)d_ws;
    float*          temb = (float*)(ws + WS_TEMB);
    __hip_bfloat16* hb   = (__hip_bfloat16*)(ws + WS_H);
    __hip_bfloat16* W1at = (__hip_bfloat16*)(ws + WS_W1AT);
    __hip_bfloat16* W2at = (__hip_bfloat16*)(ws + WS_W2AT);
    __hip_bfloat16* W1bt = (__hip_bfloat16*)(ws + WS_W1BT);
    __hip_bfloat16* W2bt = (__hip_bfloat16*)(ws + WS_W2BT);

    float* out      = (float*)d_out;
    float* out_pos  = out;                 // 10000*3
    float* out_atom = out + 30000;         // 10000*100
    float* out_bond = out + 1030000;       // 320000*5
    float* out_nf   = out + 2630000;       // 10000*256

    // weight transpose+cast (tiny)
    tcast_kernel<<<256, 256, 0, stream>>>(atom_w1, W1at, 256, 256, 256);
    tcast_kernel<<<112, 256, 0, stream>>>(atom_w2, W2at, 256, 100, 112);
    tcast_kernel<<<512, 256, 0, stream>>>(bond_w1, W1bt, 512, 256, 256);
    tcast_kernel<<< 16, 256, 0, stream>>>(bond_w2, W2bt, 256,   5,  16);
    // timestep embedding
    temb_kernel<<<128, 128, 0, stream>>>(t_disc, temb);
    // h = nf + temb[batch] (bf16), nf copy
    h_kernel<<<1250, 256, 0, stream>>>(node_features, batch, temb, hb, out_nf);
    // pos copy
    pos_copy_kernel<<<30, 256, 0, stream>>>((const float4*)pos_pred, (float4*)out_pos);
    // atom MLP: M=10000, K=256, hidden 256, out 100 (pad 112)
    mlp_kernel<8, false, 7, 100><<<157, 256, 0, stream>>>(
        hb, W1at, W2at, atom_b1, atom_b2, nullptr, N_NODES, out_atom);
    // bond MLP: M=320000 edges, K=512 (gathered h[row];h[col]), hidden 256, out 5 (pad 16)
    mlp_kernel<16, true, 1, 5><<<5000, 256, 0, stream>>>(
        hb, W1bt, W2bt, bond_b1, bond_b2, edge_index, N_EDGES, out_bond);
}

// Round 2
// 220.813 us; speedup vs baseline: 1.3482x; 1.3482x over previous
//
#include <hip/hip_runtime.h>
#include <hip/hip_bf16.h>

typedef __bf16 bf16x8 __attribute__((ext_vector_type(8)));
typedef float  f32x4  __attribute__((ext_vector_type(4)));

#define N_NODES 10000
#define N_EDGES 320000

// workspace byte offsets (16B aligned)
#define WS_TEMB   0u         // 128*256*4
#define WS_H      131072u    // 10000*256*2 bf16
#define WS_W1AT   5251072u   // atom W1^T [256][256] bf16
#define WS_W2AT   5382144u   // atom W2^T [112][256] bf16
#define WS_W1BT   5439488u   // bond W1^T [256][512] bf16
#define WS_W2BT   5701632u   // bond W2^T [16][256] bf16

// ---------------- prep: 4 weight transposes + timestep embedding ----------------
__global__ void prep_kernel(const float* __restrict__ aw1, const float* __restrict__ aw2,
                            const float* __restrict__ bw1, const float* __restrict__ bw2,
                            const float* __restrict__ t,
                            __hip_bfloat16* __restrict__ W1a, __hip_bfloat16* __restrict__ W2a,
                            __hip_bfloat16* __restrict__ W1b, __hip_bfloat16* __restrict__ W2b,
                            float* __restrict__ temb)
{
    int blk = blockIdx.x;
    if (blk < 256) {                       // atom w1 -> [256 n][256 k]
        int i = blk * 256 + threadIdx.x;
        int n = i >> 8, k = i & 255;
        W1a[i] = __float2bfloat16(aw1[k * 256 + n]);
    } else if (blk < 368) {                // atom w2 [256][100] -> [112 n][256 k]
        int i = (blk - 256) * 256 + threadIdx.x;
        int n = i >> 8, k = i & 255;
        W2a[i] = __float2bfloat16(n < 100 ? aw2[k * 100 + n] : 0.0f);
    } else if (blk < 880) {                // bond w1 [512][256] -> [256 n][512 k]
        int i = (blk - 368) * 256 + threadIdx.x;
        int n = i >> 9, k = i & 511;
        W1b[i] = __float2bfloat16(bw1[k * 256 + n]);
    } else if (blk < 896) {                // bond w2 [256][5] -> [16 n][256 k]
        int i = (blk - 880) * 256 + threadIdx.x;
        int n = i >> 8, k = i & 255;
        W2b[i] = __float2bfloat16(n < 5 ? bw2[k * 5 + n] : 0.0f);
    } else {                               // temb: blocks 896..959
        int q = blk - 896;
        int b = q * 2 + (threadIdx.x >> 7);
        int i = threadIdx.x & 127;
        float freq = expf((float)i * (-9.210340371976184f / 127.0f));
        float ang  = t[b] * freq;
        temb[b * 256 + i]       = sinf(ang);
        temb[b * 256 + 128 + i] = cosf(ang);
    }
}

// ---------------- h = bf16(nf + temb[batch]) + nf copy + pos copy ----------------
__global__ void h_kernel(const float* __restrict__ nf, const int* __restrict__ batch,
                         const float* __restrict__ temb, __hip_bfloat16* __restrict__ hb,
                         float* __restrict__ out_nf,
                         const float4* __restrict__ pos_src, float4* __restrict__ pos_dst)
{
    int blk = blockIdx.x;
    if (blk >= 1250) {                     // pos copy: 30000 floats
        int j = (blk - 1250) * 256 + threadIdx.x;
        if (j < 7500) pos_dst[j] = pos_src[j];
        return;
    }
    int i = blk * 256 + threadIdx.x;       // one thread per 8 elems
    int n = i >> 5;
    int c = (i & 31) << 3;
    const float4* p = (const float4*)(nf + (size_t)n * 256 + c);
    float4 v0 = p[0], v1 = p[1];
    int b = batch[n];
    const float4* q = (const float4*)(temb + (size_t)b * 256 + c);
    float4 t0 = q[0], t1 = q[1];
    union { int4 i4; __hip_bfloat16 h[8]; } u;
    u.h[0] = __float2bfloat16(v0.x + t0.x);
    u.h[1] = __float2bfloat16(v0.y + t0.y);
    u.h[2] = __float2bfloat16(v0.z + t0.z);
    u.h[3] = __float2bfloat16(v0.w + t0.w);
    u.h[4] = __float2bfloat16(v1.x + t1.x);
    u.h[5] = __float2bfloat16(v1.y + t1.y);
    u.h[6] = __float2bfloat16(v1.z + t1.z);
    u.h[7] = __float2bfloat16(v1.w + t1.w);
    *(int4*)((char*)hb + (size_t)n * 512 + (size_t)c * 2) = u.i4;
    float4* o = (float4*)(out_nf + (size_t)n * 256 + c);
    o[0] = v0; o[1] = v1;
}

// ---------------- async global->LDS 16B ----------------
__device__ __forceinline__ void gload16(const void* g, void* l)
{
    __builtin_amdgcn_global_load_lds(
        (const __attribute__((address_space(1))) unsigned int*)g,
        (__attribute__((address_space(3))) unsigned int*)l, 16, 0, 0);
}

// ---------------- fused 2-layer MLP, 2-phase prefetch pipeline ----------------
// Tile: 64 rows x 256 cols, BK=64, KSTEPS = K/64. 4 waves, wave w owns n-slice [w*64,+64).
// LDS (dynamic 81920B): buf0 @0, buf1 @40960. In buf: A [64 r][128B] @0, B [256 n][128B] @8192.
// Rows are 128B; swizzle: LDS chunk kc holds logical chunk (kc ^ (row&7)) -- applied on the
// global SOURCE address at stage time (global_load_lds dest stays linear) and on frag ds_reads.
// Hidden relu(L1+b1) bf16 [64][264] aliases buf0 after the K-loop.
template<int KSTEPS, bool GATHER, int N2F, int N2REAL>
__global__ __launch_bounds__(256, 2) void mlp_kernel(
    const __hip_bfloat16* __restrict__ hb,    // [N_NODES][256] bf16
    const __hip_bfloat16* __restrict__ w1t,   // [256 n][KSTEPS*64 k] bf16
    const __hip_bfloat16* __restrict__ w2t,   // [N2F*16 n][256 k] bf16
    const float* __restrict__ b1,             // [256]
    const float* __restrict__ b2,             // [N2REAL]
    const int*  __restrict__ eidx,            // GATHER: [2][N_EDGES]
    int M,
    float* __restrict__ out)                  // [M][N2REAL]
{
    extern __shared__ char lds[];
    const int t  = threadIdx.x;
    const int w  = t >> 6;
    const int l  = t & 63;
    const int m0 = blockIdx.x * 64;

    // lane-constant source swizzle: staged row&7 == l>>3, staged chunk == l&7
    const int swz = (((l & 7) ^ (l >> 3)) << 4);

    // A-stage sources: instr i (0,1) stages rows i*32 + w*8 + (l>>3)
    const char* hbase = (const char*)hb;
    int srcA[2][2];
    #pragma unroll
    for (int i = 0; i < 2; ++i) {
        int am = i * 32 + w * 8 + (l >> 3);
        if (GATHER) {
            int e = m0 + am;
            srcA[i][0] = eidx[e] * 512 + swz;
            srcA[i][1] = eidx[N_EDGES + e] * 512 + swz;
        } else {
            int r = m0 + am; if (r > M - 1) r = M - 1;
            srcA[i][0] = r * 512 + swz;
            srcA[i][1] = srcA[i][0];
        }
    }
    // B-stage sources: instr i (0..7) stages n-rows i*32 + w*8 + (l>>3)
    const char* w1base = (const char*)w1t;
    int srcB[8];
    #pragma unroll
    for (int i = 0; i < 8; ++i) {
        int n = i * 32 + w * 8 + (l >> 3);
        srcB[i] = n * (KSTEPS * 128) + swz;
    }

    f32x4 acc[4][4];
    const f32x4 zero4 = {0.f, 0.f, 0.f, 0.f};
    #pragma unroll
    for (int i = 0; i < 4; ++i)
        #pragma unroll
        for (int j = 0; j < 4; ++j) acc[i][j] = zero4;

    auto STAGE = [&](int ks, char* buf) {
        int koffA = (GATHER ? (ks & (KSTEPS / 2 - 1)) : ks) * 128;
        int side  = (GATHER && ks >= KSTEPS / 2) ? 1 : 0;
        #pragma unroll
        for (int i = 0; i < 2; ++i)
            gload16(hbase + (long)(srcA[i][side] + koffA), buf + (i * 4 + w) * 1024);
        int koffB = ks * 128;
        #pragma unroll
        for (int i = 0; i < 8; ++i)
            gload16(w1base + (long)(srcB[i] + koffB), buf + 8192 + (i * 4 + w) * 1024);
    };

    STAGE(0, lds);
    __syncthreads();

    #pragma unroll
    for (int ks = 0; ks < KSTEPS; ++ks) {
        char* cur = lds + (ks & 1) * 40960;
        if (ks + 1 < KSTEPS) STAGE(ks + 1, lds + ((ks + 1) & 1) * 40960);
        // fragments (chunk j = k1*4 + (l>>4), row&7 == l&7)
        bf16x8 af[4][2];
        #pragma unroll
        for (int mi = 0; mi < 4; ++mi)
            #pragma unroll
            for (int k1 = 0; k1 < 2; ++k1)
                af[mi][k1] = *(const bf16x8*)(cur + (mi * 16 + (l & 15)) * 128 +
                                              (((k1 * 4 + (l >> 4)) ^ (l & 7)) << 4));
        #pragma unroll
        for (int ni = 0; ni < 4; ++ni) {
            #pragma unroll
            for (int k1 = 0; k1 < 2; ++k1) {
                bf16x8 bfr = *(const bf16x8*)(cur + 8192 + (w * 64 + ni * 16 + (l & 15)) * 128 +
                                              (((k1 * 4 + (l >> 4)) ^ (l & 7)) << 4));
                #pragma unroll
                for (int mi = 0; mi < 4; ++mi)
                    acc[mi][ni] = __builtin_amdgcn_mfma_f32_16x16x32_bf16(af[mi][k1], bfr, acc[mi][ni], 0, 0, 0);
            }
        }
        __syncthreads();   // drains prefetch (vmcnt) + frag reads (lgkm), then barrier
    }

    // epilogue 1: hidden = relu(acc + b1) -> bf16 LDS [64][264] @ buf0 (KSTEPS even -> last reads were buf1)
    __hip_bfloat16* Hid = (__hip_bfloat16*)lds;
    {
        float b1v[4];
        #pragma unroll
        for (int ni = 0; ni < 4; ++ni) b1v[ni] = b1[w * 64 + ni * 16 + (l & 15)];
        #pragma unroll
        for (int mi = 0; mi < 4; ++mi)
            #pragma unroll
            for (int ni = 0; ni < 4; ++ni)
                #pragma unroll
                for (int r = 0; r < 4; ++r) {
                    int m = mi * 16 + (l >> 4) * 4 + r;        // D row (m89 layout)
                    int n = w * 64 + ni * 16 + (l & 15);       // D col
                    float v = acc[mi][ni][r] + b1v[ni];
                    Hid[m * 264 + n] = __float2bfloat16(fmaxf(v, 0.0f));
                }
    }
    __syncthreads();

    // layer 2: wave w owns out rows [w*16,+16); K=256 (8 steps of 32); W2^T frags from global (L2-hot)
    f32x4 acc2[N2F];
    #pragma unroll
    for (int i = 0; i < N2F; ++i) acc2[i] = zero4;
    const char* w2base = (const char*)w2t;
    #pragma unroll
    for (int ks = 0; ks < 8; ++ks) {
        bf16x8 a2 = *(const bf16x8*)(lds + (w * 16 + (l & 15)) * 528 + ks * 64 + (l >> 4) * 16);
        #pragma unroll
        for (int nf2 = 0; nf2 < N2F; ++nf2) {
            bf16x8 b2f = *(const bf16x8*)(w2base + (nf2 * 16 + (l & 15)) * 512 + ks * 64 + (l >> 4) * 16);
            acc2[nf2] = __builtin_amdgcn_mfma_f32_16x16x32_bf16(a2, b2f, acc2[nf2], 0, 0, 0);
        }
    }
    #pragma unroll
    for (int nf2 = 0; nf2 < N2F; ++nf2) {
        int n = nf2 * 16 + (l & 15);
        if (n < N2REAL) {
            float b2v = b2[n];
            #pragma unroll
            for (int r = 0; r < 4; ++r) {
                int m  = w * 16 + (l >> 4) * 4 + r;
                int gm = m0 + m;
                if (gm < M)
                    out[(long)gm * N2REAL + n] = acc2[nf2][r] + b2v;
            }
        }
    }
}

// ---------------- launch ----------------
extern "C" void kernel_launch(void* const* d_in, const int* in_sizes, int n_in,
                              void* d_out, int out_size, void* d_ws, size_t ws_size,
                              hipStream_t stream)
{
    const float* node_features = (const float*)d_in[0];
    const float* pos_pred      = (const float*)d_in[1];
    const int*   edge_index    = (const int*)d_in[2];
    const int*   batch         = (const int*)d_in[3];
    const float* t_disc        = (const float*)d_in[4];
    const float* atom_w1       = (const float*)d_in[5];
    const float* atom_b1       = (const float*)d_in[6];
    const float* atom_w2       = (const float*)d_in[7];
    const float* atom_b2       = (const float*)d_in[8];
    const float* bond_w1       = (const float*)d_in[9];
    const float* bond_b1       = (const float*)d_in[10];
    const float* bond_w2       = (const float*)d_in[11];
    const float* bond_b2       = (const float*)d_in[12];

    char* ws = (char*)d_ws;
    float*          temb = (float*)(ws + WS_TEMB);
    __hip_bfloat16* hbf  = (__hip_bfloat16*)(ws + WS_H);
    __hip_bfloat16* W1at = (__hip_bfloat16*)(ws + WS_W1AT);
    __hip_bfloat16* W2at = (__hip_bfloat16*)(ws + WS_W2AT);
    __hip_bfloat16* W1bt = (__hip_bfloat16*)(ws + WS_W1BT);
    __hip_bfloat16* W2bt = (__hip_bfloat16*)(ws + WS_W2BT);

    float* out      = (float*)d_out;
    float* out_pos  = out;                 // 10000*3
    float* out_atom = out + 30000;         // 10000*100
    float* out_bond = out + 1030000;       // 320000*5
    float* out_nf   = out + 2630000;       // 10000*256

    prep_kernel<<<960, 256, 0, stream>>>(atom_w1, atom_w2, bond_w1, bond_w2, t_disc,
                                         W1at, W2at, W1bt, W2bt, temb);
    h_kernel<<<1280, 256, 0, stream>>>(node_features, batch, temb, hbf, out_nf,
                                       (const float4*)pos_pred, (float4*)out_pos);
    // atom MLP: M=10000, K=256 (4 steps), out 100 (pad 112)
    mlp_kernel<4, false, 7, 100><<<157, 256, 81920, stream>>>(
        hbf, W1at, W2at, atom_b1, atom_b2, nullptr, N_NODES, out_atom);
    // bond MLP: M=320000, K=512 (8 steps, gathered h[row];h[col]), out 5 (pad 16)
    mlp_kernel<8, true, 1, 5><<<5000, 256, 81920, stream>>>(
        hbf, W1bt, W2bt, bond_b1, bond_b2, edge_index, N_EDGES, out_bond);
}

// Round 11
// 214.590 us; speedup vs baseline: 1.3873x; 1.0290x over previous
//
#include <hip/hip_runtime.h>
#include <hip/hip_bf16.h>

typedef __bf16 bf16x8 __attribute__((ext_vector_type(8)));
typedef float  f32x4  __attribute__((ext_vector_type(4)));

#define N_NODES 10000
#define N_EDGES 320000

// workspace byte offsets (16B aligned)
#define WS_TEMB   0u         // 128*256*4
#define WS_H      131072u    // 10000*256*2 bf16
#define WS_W1AT   5251072u   // atom W1^T [256][256] bf16
#define WS_W2AT   5382144u   // atom W2^T [112][256] bf16
#define WS_W1BT   5439488u   // bond W1^T [256][512] bf16
#define WS_W2BT   5701632u   // bond W2^T [16][256] bf16

// ---------------- prep: 4 weight transposes + timestep embedding ----------------
__global__ void prep_kernel(const float* __restrict__ aw1, const float* __restrict__ aw2,
                            const float* __restrict__ bw1, const float* __restrict__ bw2,
                            const float* __restrict__ t,
                            __hip_bfloat16* __restrict__ W1a, __hip_bfloat16* __restrict__ W2a,
                            __hip_bfloat16* __restrict__ W1b, __hip_bfloat16* __restrict__ W2b,
                            float* __restrict__ temb)
{
    int blk = blockIdx.x;
    if (blk < 256) {                       // atom w1 -> [256 n][256 k]
        int i = blk * 256 + threadIdx.x;
        int n = i >> 8, k = i & 255;
        W1a[i] = __float2bfloat16(aw1[k * 256 + n]);
    } else if (blk < 368) {                // atom w2 [256][100] -> [112 n][256 k]
        int i = (blk - 256) * 256 + threadIdx.x;
        int n = i >> 8, k = i & 255;
        W2a[i] = __float2bfloat16(n < 100 ? aw2[k * 100 + n] : 0.0f);
    } else if (blk < 880) {                // bond w1 [512][256] -> [256 n][512 k]
        int i = (blk - 368) * 256 + threadIdx.x;
        int n = i >> 9, k = i & 511;
        W1b[i] = __float2bfloat16(bw1[k * 256 + n]);
    } else if (blk < 896) {                // bond w2 [256][5] -> [16 n][256 k]
        int i = (blk - 880) * 256 + threadIdx.x;
        int n = i >> 8, k = i & 255;
        W2b[i] = __float2bfloat16(n < 5 ? bw2[k * 5 + n] : 0.0f);
    } else {                               // temb: blocks 896..959
        int q = blk - 896;
        int b = q * 2 + (threadIdx.x >> 7);
        int i = threadIdx.x & 127;
        float freq = expf((float)i * (-9.210340371976184f / 127.0f));
        float ang  = t[b] * freq;
        temb[b * 256 + i]       = sinf(ang);
        temb[b * 256 + 128 + i] = cosf(ang);
    }
}

// ---------------- h = bf16(nf + temb[batch]) + nf copy + pos copy ----------------
__global__ void h_kernel(const float* __restrict__ nf, const int* __restrict__ batch,
                         const float* __restrict__ temb, __hip_bfloat16* __restrict__ hb,
                         float* __restrict__ out_nf,
                         const float4* __restrict__ pos_src, float4* __restrict__ pos_dst)
{
    int blk = blockIdx.x;
    if (blk >= 1250) {                     // pos copy: 30000 floats
        int j = (blk - 1250) * 256 + threadIdx.x;
        if (j < 7500) pos_dst[j] = pos_src[j];
        return;
    }
    int i = blk * 256 + threadIdx.x;       // one thread per 8 elems
    int n = i >> 5;
    int c = (i & 31) << 3;
    const float4* p = (const float4*)(nf + (size_t)n * 256 + c);
    float4 v0 = p[0], v1 = p[1];
    int b = batch[n];
    const float4* q = (const float4*)(temb + (size_t)b * 256 + c);
    float4 t0 = q[0], t1 = q[1];
    union { int4 i4; __hip_bfloat16 h[8]; } u;
    u.h[0] = __float2bfloat16(v0.x + t0.x);
    u.h[1] = __float2bfloat16(v0.y + t0.y);
    u.h[2] = __float2bfloat16(v0.z + t0.z);
    u.h[3] = __float2bfloat16(v0.w + t0.w);
    u.h[4] = __float2bfloat16(v1.x + t1.x);
    u.h[5] = __float2bfloat16(v1.y + t1.y);
    u.h[6] = __float2bfloat16(v1.z + t1.z);
    u.h[7] = __float2bfloat16(v1.w + t1.w);
    *(int4*)((char*)hb + (size_t)n * 512 + (size_t)c * 2) = u.i4;
    float4* o = (float4*)(out_nf + (size_t)n * 256 + c);
    o[0] = v0; o[1] = v1;
}

// ---------------- async global->LDS 16B ----------------
__device__ __forceinline__ void gload16(const void* g, void* l)
{
    __builtin_amdgcn_global_load_lds(
        (const __attribute__((address_space(1))) unsigned int*)g,
        (__attribute__((address_space(3))) unsigned int*)l, 16, 0, 0);
}

// ---------------- fused 2-layer MLP, BM=256 tile, prefetch-before-compute ----------------
// Tile: 256 rows x 256 cols, BK=64, NT = K/64 K-tiles. 512 threads = 8 waves (2M x 4N);
// wave (wm,wn) owns rows [wm*128,+128) x cols [wn*64,+64) -> acc[8][4] 16x16 frags.
// LDS 128KB: buf0 @0, buf1 @65536. In buf: A [256 r][128B] @0, B [256 n][128B] @32768.
// 128B rows; XOR swizzle chunk^= (row&7), applied on the global SOURCE address at stage
// time (global_load_lds dest stays linear) and on all frag ds_reads (rule #21).
// Pipeline per K-tile: __syncthreads (drains PREVIOUS tile's loads -- issued a full
// compute phase ago, so free in steady state) -> issue STAGE(kt+1) -> COMPUTE(kt).
// After K-loop: hidden relu(L1+b1) bf16 [256 r][512B] aliases the whole LDS (same XOR
// swizzle), then layer 2 (K=256, 8 k-steps) with W2^T frags direct from global (L2-hot).
template<int NT, bool GATHER, int N2F, int N2REAL>
__global__ __launch_bounds__(512, 2) void mlp_kernel(
    const __hip_bfloat16* __restrict__ hb,    // [N_NODES][256] bf16
    const __hip_bfloat16* __restrict__ w1t,   // [256 n][NT*64 k] bf16
    const __hip_bfloat16* __restrict__ w2t,   // [N2F*16 n][256 k] bf16
    const float* __restrict__ b1,             // [256]
    const float* __restrict__ b2,             // [N2REAL]
    const int*  __restrict__ eidx,            // GATHER: [2][N_EDGES]
    int M,
    float* __restrict__ out)                  // [M][N2REAL]
{
    extern __shared__ char lds[];
    const int t   = threadIdx.x;
    const int wid = t >> 6;                 // 0..7
    const int l   = t & 63;
    const int wm  = wid >> 2;               // 0..1
    const int wn  = wid & 3;                // 0..3
    const int m0  = blockIdx.x * 256;

    // lane-constant source swizzle byte: chunk (t&7) XOR row-low-3 ((t>>3)&7), *16B
    const int swz = (((t & 7) ^ ((t >> 3) & 7)) << 4);

    // A-stage sources: instr i (0..3) stages rows i*64 + (t>>3), one 16B chunk each
    const char* hbase = (const char*)hb;
    int srcA[4][2];
    #pragma unroll
    for (int i = 0; i < 4; ++i) {
        int am = i * 64 + (t >> 3);
        if (GATHER) {
            int e = m0 + am;
            srcA[i][0] = eidx[e] * 512 + swz;
            srcA[i][1] = eidx[N_EDGES + e] * 512 + swz;
        } else {
            int r = m0 + am; if (r > M - 1) r = M - 1;
            srcA[i][0] = r * 512 + swz;
            srcA[i][1] = srcA[i][0];
        }
    }
    // B-stage sources: instr i (0..3) stages n-rows i*64 + (t>>3)
    const char* w1base = (const char*)w1t;
    int srcB[4];
    #pragma unroll
    for (int i = 0; i < 4; ++i)
        srcB[i] = (i * 64 + (t >> 3)) * (NT * 128) + swz;

    f32x4 acc[8][4];
    #pragma unroll
    for (int i = 0; i < 8; ++i)
        #pragma unroll
        for (int j = 0; j < 4; ++j) acc[i][j] = f32x4{0.f, 0.f, 0.f, 0.f};

    auto STAGE = [&](int ks, char* buf) {
        int side  = (GATHER && ks >= NT / 2) ? 1 : 0;
        int koffA = (GATHER ? (ks & (NT / 2 - 1)) : ks) * 128;
        #pragma unroll
        for (int i = 0; i < 4; ++i)
            gload16(hbase + (long)(srcA[i][side] + koffA), buf + i * 8192 + wid * 1024);
        int koffB = ks * 128;
        #pragma unroll
        for (int i = 0; i < 4; ++i)
            gload16(w1base + (long)(srcB[i] + koffB), buf + 32768 + i * 8192 + wid * 1024);
    };

    STAGE(0, lds);

    for (int kt = 0; kt < NT; ++kt) {
        __syncthreads();   // drains kt's loads (in flight for a whole compute phase) +
                           // confirms all waves finished reading buf[(kt+1)&1]
        if (kt + 1 < NT) STAGE(kt + 1, lds + (((kt + 1) & 1) << 16));
        const char* cur = lds + ((kt & 1) << 16);
        #pragma unroll
        for (int k1 = 0; k1 < 2; ++k1) {
            const int jx = (k1 * 4 + (l >> 4)) ^ (l & 7);   // swizzled chunk (row&7 == l&7)
            bf16x8 af[8];
            #pragma unroll
            for (int mi = 0; mi < 8; ++mi) {
                int r = wm * 128 + mi * 16 + (l & 15);
                af[mi] = *(const bf16x8*)(cur + r * 128 + (jx << 4));
            }
            #pragma unroll
            for (int ni = 0; ni < 4; ++ni) {
                int rn = wn * 64 + ni * 16 + (l & 15);
                bf16x8 bfr = *(const bf16x8*)(cur + 32768 + rn * 128 + (jx << 4));
                #pragma unroll
                for (int mi = 0; mi < 8; ++mi)
                    acc[mi][ni] = __builtin_amdgcn_mfma_f32_16x16x32_bf16(af[mi], bfr, acc[mi][ni], 0, 0, 0);
            }
        }
    }

    // ---- epilogue 1: hidden = relu(acc + b1) -> bf16 LDS [256 r][512B], XOR-swizzled ----
    __syncthreads();       // all waves done with both buffers before aliasing as H
    {
        float b1v[4];
        #pragma unroll
        for (int ni = 0; ni < 4; ++ni) b1v[ni] = b1[wn * 64 + ni * 16 + (l & 15)];
        #pragma unroll
        for (int mi = 0; mi < 8; ++mi)
            #pragma unroll
            for (int ni = 0; ni < 4; ++ni)
                #pragma unroll
                for (int r = 0; r < 4; ++r) {
                    int m = wm * 128 + mi * 16 + (l >> 4) * 4 + r;   // D row (m89 layout)
                    int n = wn * 64 + ni * 16 + (l & 15);            // D col
                    float v = fmaxf(acc[mi][ni][r] + b1v[ni], 0.0f);
                    int byte = m * 512 + ((((n >> 3) ^ (m & 7)) << 4)) + ((n & 7) << 1);
                    *(__hip_bfloat16*)(lds + byte) = __float2bfloat16(v);
                }
    }
    __syncthreads();

    // ---- layer 2: wave owns out rows [wid*32,+32); K=256 (8 k-steps); B from global ----
    f32x4 acc2[2][N2F];
    #pragma unroll
    for (int i = 0; i < 2; ++i)
        #pragma unroll
        for (int j = 0; j < N2F; ++j) acc2[i][j] = f32x4{0.f, 0.f, 0.f, 0.f};
    const char* w2base = (const char*)w2t;
    #pragma unroll
    for (int ks = 0; ks < 8; ++ks) {
        const int jx2 = (ks * 4 + (l >> 4)) ^ (l & 7);
        bf16x8 a2[2];
        #pragma unroll
        for (int mi2 = 0; mi2 < 2; ++mi2) {
            int r2 = wid * 32 + mi2 * 16 + (l & 15);
            a2[mi2] = *(const bf16x8*)(lds + r2 * 512 + (jx2 << 4));
        }
        #pragma unroll
        for (int nf2 = 0; nf2 < N2F; ++nf2) {
            bf16x8 b2f = *(const bf16x8*)(w2base + (nf2 * 16 + (l & 15)) * 512 + ks * 64 + (l >> 4) * 16);
            #pragma unroll
            for (int mi2 = 0; mi2 < 2; ++mi2)
                acc2[mi2][nf2] = __builtin_amdgcn_mfma_f32_16x16x32_bf16(a2[mi2], b2f, acc2[mi2][nf2], 0, 0, 0);
        }
    }
    #pragma unroll
    for (int nf2 = 0; nf2 < N2F; ++nf2) {
        int n = nf2 * 16 + (l & 15);
        if (n < N2REAL) {
            float b2v = b2[n];
            #pragma unroll
            for (int mi2 = 0; mi2 < 2; ++mi2)
                #pragma unroll
                for (int r = 0; r < 4; ++r) {
                    int gm = m0 + wid * 32 + mi2 * 16 + (l >> 4) * 4 + r;
                    if (gm < M)
                        out[(long)gm * N2REAL + n] = acc2[mi2][nf2][r] + b2v;
                }
        }
    }
}

// ---------------- launch ----------------
extern "C" void kernel_launch(void* const* d_in, const int* in_sizes, int n_in,
                              void* d_out, int out_size, void* d_ws, size_t ws_size,
                              hipStream_t stream)
{
    const float* node_features = (const float*)d_in[0];
    const float* pos_pred      = (const float*)d_in[1];
    const int*   edge_index    = (const int*)d_in[2];
    const int*   batch         = (const int*)d_in[3];
    const float* t_disc        = (const float*)d_in[4];
    const float* atom_w1       = (const float*)d_in[5];
    const float* atom_b1       = (const float*)d_in[6];
    const float* atom_w2       = (const float*)d_in[7];
    const float* atom_b2       = (const float*)d_in[8];
    const float* bond_w1       = (const float*)d_in[9];
    const float* bond_b1       = (const float*)d_in[10];
    const float* bond_w2       = (const float*)d_in[11];
    const float* bond_b2       = (const float*)d_in[12];

    char* ws = (char*)d_ws;
    float*          temb = (float*)(ws + WS_TEMB);
    __hip_bfloat16* hbf  = (__hip_bfloat16*)(ws + WS_H);
    __hip_bfloat16* W1at = (__hip_bfloat16*)(ws + WS_W1AT);
    __hip_bfloat16* W2at = (__hip_bfloat16*)(ws + WS_W2AT);
    __hip_bfloat16* W1bt = (__hip_bfloat16*)(ws + WS_W1BT);
    __hip_bfloat16* W2bt = (__hip_bfloat16*)(ws + WS_W2BT);

    float* out      = (float*)d_out;
    float* out_pos  = out;                 // 10000*3
    float* out_atom = out + 30000;         // 10000*100
    float* out_bond = out + 1030000;       // 320000*5
    float* out_nf   = out + 2630000;       // 10000*256

    prep_kernel<<<960, 256, 0, stream>>>(atom_w1, atom_w2, bond_w1, bond_w2, t_disc,
                                         W1at, W2at, W1bt, W2bt, temb);
    h_kernel<<<1280, 256, 0, stream>>>(node_features, batch, temb, hbf, out_nf,
                                       (const float4*)pos_pred, (float4*)out_pos);
    // atom MLP: M=10000, K=256 (NT=4), out 100 (pad 112)
    mlp_kernel<4, false, 7, 100><<<40, 512, 131072, stream>>>(
        hbf, W1at, W2at, atom_b1, atom_b2, nullptr, N_NODES, out_atom);
    // bond MLP: M=320000, K=512 (NT=8, gathered h[row];h[col]), out 5 (pad 16)
    mlp_kernel<8, true, 1, 5><<<1250, 512, 131072, stream>>>(
        hbf, W1bt, W2bt, bond_b1, bond_b2, edge_index, N_EDGES, out_bond);
}